// Round 13
// baseline (192.084 us; speedup 1.0000x reference)
//
#include <hip/hip_runtime.h>

// GCN 2-layer forward. Fixed-stride bucketed padded-CSR build (bin/fillb),
// gather-only aggregation with PLANAR bf16 message rows: features 0..15 in
// plane A, 16..31 in plane B (32B half-rows, 3.2MB/plane). gather_q runs as
// two grid-halves (plane A blocks dispatch before plane B) so each half's
// random footprint fits the 4MB per-XCD L2. gather_out loads adj once into
// registers and does two sequential plane phases.
//
// R12 bug: ebuf aliased qa, and qa's sentinel row (offset 8N = 800000 uints)
// sat INSIDE ebuf's 1.4M-uint extent -> bin clobbered the sentinel zeros ->
// pad-slot reads returned garbage. Fix: dedicated ebuf region (~33 MB total,
// within budget per R7/R8's ~40 MB).

#define CAP 32
#define OVF_MAX 65536
#define SH_BITS 8
#define SH 256          // nodes per bucket
#define BCAP 3584       // edge capacity per bucket (E/B ~ 3070, sigma ~ 55)
#define EPB 4096        // edges per bin block
#define EPT 16          // edges per thread in bin

typedef __attribute__((ext_vector_type(4))) float vf4;

__device__ __forceinline__ unsigned bf16rn(float f) {
    unsigned u = __float_as_uint(f);
    return (u + 0x7fffu + ((u >> 16) & 1u)) >> 16;   // round-to-nearest-even
}
__device__ __forceinline__ unsigned pack2(float f0, float f1) {
    return (bf16rn(f1) << 16) | bf16rn(f0);
}
__device__ __forceinline__ void accu(float2& a, unsigned v) {
    a.x += __uint_as_float(v << 16);
    a.y += __uint_as_float(v & 0xffff0000u);
}

// ga/gb/qa/qb pre-offset to sentinel row N (8 uints each).
__global__ void init_kernel(int* __restrict__ bcur, int* __restrict__ ovfcnt,
                            unsigned* __restrict__ ga, unsigned* __restrict__ gb,
                            unsigned* __restrict__ qa, unsigned* __restrict__ qb, int B) {
    int i = blockIdx.x * blockDim.x + threadIdx.x;
    if (i < B) bcur[i] = i * BCAP;
    if (i == 0) *ovfcnt = 0;
    if (i < 8) { ga[i] = 0u; gb[i] = 0u; qa[i] = 0u; qb[i] = 0u; }
}

// Bin edges into fixed-stride bucket runs, payload packed to 4B:
// (dst&255)<<24 | src. Histogram atomicAdd return = block-local rank.
// NT loads: src/dst are read-once streams.
__global__ __launch_bounds__(256) void bin_kernel(const int* __restrict__ src,
                                                  const int* __restrict__ dst,
                                                  int* __restrict__ bcur,
                                                  unsigned int* __restrict__ ebuf,
                                                  int* __restrict__ ovfcnt,
                                                  int* __restrict__ ovf, int E, int B) {
    __shared__ int h[512];
    __shared__ int gp[512];
    for (int b = threadIdx.x; b < B; b += 256) h[b] = 0;
    __syncthreads();
    int base = blockIdx.x * EPB;
    int s[EPT], d[EPT], r[EPT];
#pragma unroll
    for (int k = 0; k < EPT; ++k) {
        int e = base + k * 256 + threadIdx.x;
        bool ok = e < E;
        s[k] = ok ? __builtin_nontemporal_load(src + e) : 0;
        d[k] = ok ? __builtin_nontemporal_load(dst + e) : 0;
        r[k] = ok ? atomicAdd(&h[d[k] >> SH_BITS], 1) : 0;
    }
    __syncthreads();
    for (int b = threadIdx.x; b < B; b += 256)
        if (h[b]) gp[b] = atomicAdd(&bcur[b], h[b]);
    __syncthreads();
#pragma unroll
    for (int k = 0; k < EPT; ++k) {
        int e = base + k * 256 + threadIdx.x;
        if (e < E) {
            int bk = d[k] >> SH_BITS;
            int pos = gp[bk] + r[k];
            if (pos < (bk + 1) * BCAP)
                ebuf[pos] = ((unsigned)(d[k] & (SH - 1)) << 24) | (unsigned)s[k];
            else { int o = atomicAdd(ovfcnt, 1); if (o < OVF_MAX) { ovf[2 * o] = s[k]; ovf[2 * o + 1] = d[k]; } }
        }
    }
}

// One block per bucket: padded-CSR window in LDS, sentinel-N pad, dense
// stream-out; deg<16 rows skip their all-sentinel second half.
__global__ __launch_bounds__(256) void fillb_kernel(const unsigned int* __restrict__ ebuf,
                                                    const int* __restrict__ bcur,
                                                    int* __restrict__ adj,
                                                    float* __restrict__ dinv,
                                                    int* __restrict__ ovfcnt,
                                                    int* __restrict__ ovf, int N) {
    __shared__ int lcnt[SH];
    __shared__ int ladj[SH * CAP];     // 32 KB
    int b = blockIdx.x;
    for (int i = threadIdx.x; i < SH; i += 256) lcnt[i] = 0;
    for (int i = threadIdx.x; i < SH * CAP; i += 256) ladj[i] = N;
    __syncthreads();
    int beg = b * BCAP;
    int tot = bcur[b] - beg;
    int m = tot < BCAP ? tot : BCAP;
    for (int i = threadIdx.x; i < m; i += 256) {
        unsigned p = __builtin_nontemporal_load(ebuf + beg + i);
        int ld = (int)(p >> 24), sidx = (int)(p & 0xFFFFFF);
        int q = atomicAdd(&lcnt[ld], 1);
        if (q < CAP) ladj[ld * CAP + q] = sidx;
        else { int o = atomicAdd(ovfcnt, 1); if (o < OVF_MAX) { ovf[2 * o] = sidx; ovf[2 * o + 1] = (b << SH_BITS) + ld; } }
    }
    __syncthreads();
    int nb0 = b << SH_BITS;
    const int4* l4 = (const int4*)ladj;
    int4* a4 = (int4*)(adj + (size_t)nb0 * CAP);
    for (int i = threadIdx.x; i < SH * CAP / 4; i += 256) {
        int row = i >> 3;
        int nd = nb0 + row;
        bool second = (i & 4) != 0;
        if (nd < N && (!second || lcnt[row] >= 16)) a4[i] = l4[i];
    }
    for (int i = threadIdx.x; i < SH; i += 256) {
        int nd = nb0 + i;
        if (nd < N) dinv[nd] = rsqrtf((float)lcnt[i] + 1.0f);   // +1 = self-loop
    }
}

// g = bf16( dinv * (x @ W1) ), planar: lane j<8 -> plane A uint j (features
// 2j,2j+1); j>=8 -> plane B uint j-8. Block = 16 nodes x 16 lanes. NT x loads.
__global__ __launch_bounds__(256) void gemm1_kernel(const float* __restrict__ x,
                                                    const float* __restrict__ W1,
                                                    const float* __restrict__ dinv,
                                                    unsigned int* __restrict__ ga,
                                                    unsigned int* __restrict__ gb, int N) {
    __shared__ float Ws[64 * 32];
    __shared__ float xs[16][64];
    int tid = threadIdx.x;
    const vf4* W4 = (const vf4*)W1;
    vf4* Ws4 = (vf4*)Ws;
    for (int i = tid; i < 512; i += 256) Ws4[i] = W4[i];
    int nb = blockIdx.x * 16;
    {
        int ln = tid >> 4, k4 = tid & 15;
        int n = nb + ln;
        vf4 v = {0.f, 0.f, 0.f, 0.f};
        if (n < N) v = __builtin_nontemporal_load((const vf4*)(x + (size_t)n * 64) + k4);
        *(vf4*)(&xs[ln][k4 * 4]) = v;
    }
    __syncthreads();
    int ln = tid >> 4, j = tid & 15;
    int n = nb + ln;
    if (n < N) {
        float s0 = 0.f, s1 = 0.f;
#pragma unroll
        for (int k = 0; k < 64; ++k) {
            float xv = xs[ln][k];
            s0 += xv * Ws[k * 32 + 2 * j];
            s1 += xv * Ws[k * 32 + 2 * j + 1];
        }
        float dv = dinv[n];
        unsigned pv = pack2(dv * s0, dv * s1);
        if (j < 8) ga[(size_t)n * 8 + j] = pv;
        else       gb[(size_t)n * 8 + (j - 8)] = pv;
    }
}

// Layer-1 aggregate + fused mid, ONE PLANE per block-half: blocks [0,nbHalf)
// do plane A (features 0..15), [nbHalf,2*nbHalf) plane B. 8 lanes per node,
// lane l = one uint (2 features). Pad slots -> sentinel row N (zeros).
__global__ __launch_bounds__(256) void gather_q_kernel(
        const int2* __restrict__ adj2,
        const int* __restrict__ ovfcnt, const int* __restrict__ ovf,
        const unsigned* __restrict__ ga, const unsigned* __restrict__ gb,
        const float* __restrict__ dinv, const float* __restrict__ b1,
        unsigned* __restrict__ qa, unsigned* __restrict__ qb, int N, int nbHalf) {
    int bid = blockIdx.x;
    int half = (bid >= nbHalf) ? 1 : 0;
    int nb = (bid - half * nbHalf) * 32;
    int tid = threadIdx.x;
    int o = tid >> 3, l = tid & 7;
    int n = nb + o;
    if (n >= N) return;
    const unsigned* gp = half ? gb : ga;
    unsigned* qp = half ? qb : qa;

    int2 h1 = adj2[(size_t)n * 16 + l];    // slots 2l, 2l+1
    int s0  = __shfl(h1.x, 0, 8), s1  = __shfl(h1.y, 0, 8);
    int s2  = __shfl(h1.x, 1, 8), s3  = __shfl(h1.y, 1, 8);
    int s4  = __shfl(h1.x, 2, 8), s5  = __shfl(h1.y, 2, 8);
    int s6  = __shfl(h1.x, 3, 8), s7  = __shfl(h1.y, 3, 8);
    int s8  = __shfl(h1.x, 4, 8), s9  = __shfl(h1.y, 4, 8);
    int s10 = __shfl(h1.x, 5, 8), s11 = __shfl(h1.y, 5, 8);
    int s12 = __shfl(h1.x, 6, 8), s13 = __shfl(h1.y, 6, 8);
    int s14 = __shfl(h1.x, 7, 8), s15 = __shfl(h1.y, 7, 8);

    unsigned w16 = gp[(size_t)n * 8 + l];  // self-loop
    unsigned w0  = gp[(size_t)s0  * 8 + l], w1  = gp[(size_t)s1  * 8 + l];
    unsigned w2  = gp[(size_t)s2  * 8 + l], w3  = gp[(size_t)s3  * 8 + l];
    unsigned w4  = gp[(size_t)s4  * 8 + l], w5  = gp[(size_t)s5  * 8 + l];
    unsigned w6  = gp[(size_t)s6  * 8 + l], w7  = gp[(size_t)s7  * 8 + l];
    unsigned w8  = gp[(size_t)s8  * 8 + l], w9  = gp[(size_t)s9  * 8 + l];
    unsigned w10 = gp[(size_t)s10 * 8 + l], w11 = gp[(size_t)s11 * 8 + l];
    unsigned w12 = gp[(size_t)s12 * 8 + l], w13 = gp[(size_t)s13 * 8 + l];
    unsigned w14 = gp[(size_t)s14 * 8 + l], w15 = gp[(size_t)s15 * 8 + l];
    float2 a = make_float2(0.f, 0.f);
    accu(a, w16);
    accu(a, w0);  accu(a, w1);  accu(a, w2);  accu(a, w3);
    accu(a, w4);  accu(a, w5);  accu(a, w6);  accu(a, w7);
    accu(a, w8);  accu(a, w9);  accu(a, w10); accu(a, w11);
    accu(a, w12); accu(a, w13); accu(a, w14); accu(a, w15);

    if (s15 != N) {                        // deg >= 16
        int2 h2 = adj2[(size_t)n * 16 + 8 + l];
        int t0  = __shfl(h2.x, 0, 8), t1  = __shfl(h2.y, 0, 8);
        int t2  = __shfl(h2.x, 1, 8), t3  = __shfl(h2.y, 1, 8);
        int t4  = __shfl(h2.x, 2, 8), t5  = __shfl(h2.y, 2, 8);
        int t6  = __shfl(h2.x, 3, 8), t7  = __shfl(h2.y, 3, 8);
        int t8  = __shfl(h2.x, 4, 8), t9  = __shfl(h2.y, 4, 8);
        int t10 = __shfl(h2.x, 5, 8), t11 = __shfl(h2.y, 5, 8);
        int t12 = __shfl(h2.x, 6, 8), t13 = __shfl(h2.y, 6, 8);
        int t14 = __shfl(h2.x, 7, 8), t15 = __shfl(h2.y, 7, 8);
        unsigned u0  = gp[(size_t)t0  * 8 + l], u1  = gp[(size_t)t1  * 8 + l];
        unsigned u2  = gp[(size_t)t2  * 8 + l], u3  = gp[(size_t)t3  * 8 + l];
        unsigned u4  = gp[(size_t)t4  * 8 + l], u5  = gp[(size_t)t5  * 8 + l];
        unsigned u6  = gp[(size_t)t6  * 8 + l], u7  = gp[(size_t)t7  * 8 + l];
        unsigned u8  = gp[(size_t)t8  * 8 + l], u9  = gp[(size_t)t9  * 8 + l];
        unsigned u10 = gp[(size_t)t10 * 8 + l], u11 = gp[(size_t)t11 * 8 + l];
        unsigned u12 = gp[(size_t)t12 * 8 + l], u13 = gp[(size_t)t13 * 8 + l];
        unsigned u14 = gp[(size_t)t14 * 8 + l], u15 = gp[(size_t)t15 * 8 + l];
        accu(a, u0);  accu(a, u1);  accu(a, u2);  accu(a, u3);
        accu(a, u4);  accu(a, u5);  accu(a, u6);  accu(a, u7);
        accu(a, u8);  accu(a, u9);  accu(a, u10); accu(a, u11);
        accu(a, u12); accu(a, u13); accu(a, u14); accu(a, u15);
    }
    int c = *ovfcnt; if (c > OVF_MAX) c = OVF_MAX;   // ~always 0
    for (int i = 0; i < c; ++i) {
        if (ovf[2 * i + 1] == n) accu(a, gp[(size_t)ovf[2 * i] * 8 + l]);
    }
    float dv = dinv[n];
    float2 bb = ((const float2*)b1)[half * 8 + l];
    float v0 = dv * a.x + bb.x, v1 = dv * a.y + bb.y;
    v0 = v0 > 0.f ? v0 : 0.f; v1 = v1 > 0.f ? v1 : 0.f;
    qp[(size_t)n * 8 + l] = pack2(dv * v0, dv * v1);
}

// Layer-2 aggregate + fused gemm2: adj indices loaded ONCE into registers,
// two sequential plane phases fill sAgg, then out = dinv*(agg @ W2) + b2 (NT).
__global__ __launch_bounds__(256) void gather_out_kernel(
        const int2* __restrict__ adj2,
        const int* __restrict__ ovfcnt, const int* __restrict__ ovf,
        const unsigned* __restrict__ qa, const unsigned* __restrict__ qb,
        const float* __restrict__ dinv,
        const float* __restrict__ W2, const float* __restrict__ b2,
        float* __restrict__ out, int N) {
    __shared__ float Ws[32 * 64];
    __shared__ float sAgg[32][36];
    int tid = threadIdx.x;
    const vf4* W4 = (const vf4*)W2;
    vf4* Ws4 = (vf4*)Ws;
    for (int i = tid; i < 512; i += 256) Ws4[i] = W4[i];
    int nb = blockIdx.x * 32;
    int o = tid >> 3, l = tid & 7;
    int n = nb + o;
    if (n < N) {
        int2 h1 = adj2[(size_t)n * 16 + l];
        int s0  = __shfl(h1.x, 0, 8), s1  = __shfl(h1.y, 0, 8);
        int s2  = __shfl(h1.x, 1, 8), s3  = __shfl(h1.y, 1, 8);
        int s4  = __shfl(h1.x, 2, 8), s5  = __shfl(h1.y, 2, 8);
        int s6  = __shfl(h1.x, 3, 8), s7  = __shfl(h1.y, 3, 8);
        int s8  = __shfl(h1.x, 4, 8), s9  = __shfl(h1.y, 4, 8);
        int s10 = __shfl(h1.x, 5, 8), s11 = __shfl(h1.y, 5, 8);
        int s12 = __shfl(h1.x, 6, 8), s13 = __shfl(h1.y, 6, 8);
        int s14 = __shfl(h1.x, 7, 8), s15 = __shfl(h1.y, 7, 8);
        bool big = (s15 != N);
        int t0 = N, t1 = N, t2 = N, t3 = N, t4 = N, t5 = N, t6 = N, t7 = N;
        int t8 = N, t9 = N, t10 = N, t11 = N, t12 = N, t13 = N, t14 = N, t15 = N;
        if (big) {
            int2 h2 = adj2[(size_t)n * 16 + 8 + l];
            t0  = __shfl(h2.x, 0, 8); t1  = __shfl(h2.y, 0, 8);
            t2  = __shfl(h2.x, 1, 8); t3  = __shfl(h2.y, 1, 8);
            t4  = __shfl(h2.x, 2, 8); t5  = __shfl(h2.y, 2, 8);
            t6  = __shfl(h2.x, 3, 8); t7  = __shfl(h2.y, 3, 8);
            t8  = __shfl(h2.x, 4, 8); t9  = __shfl(h2.y, 4, 8);
            t10 = __shfl(h2.x, 5, 8); t11 = __shfl(h2.y, 5, 8);
            t12 = __shfl(h2.x, 6, 8); t13 = __shfl(h2.y, 6, 8);
            t14 = __shfl(h2.x, 7, 8); t15 = __shfl(h2.y, 7, 8);
        }
        int c = *ovfcnt; if (c > OVF_MAX) c = OVF_MAX;
#pragma unroll
        for (int ph = 0; ph < 2; ++ph) {
            const unsigned* qp = ph ? qb : qa;
            unsigned w16 = qp[(size_t)n * 8 + l];
            unsigned w0  = qp[(size_t)s0  * 8 + l], w1  = qp[(size_t)s1  * 8 + l];
            unsigned w2  = qp[(size_t)s2  * 8 + l], w3  = qp[(size_t)s3  * 8 + l];
            unsigned w4  = qp[(size_t)s4  * 8 + l], w5  = qp[(size_t)s5  * 8 + l];
            unsigned w6  = qp[(size_t)s6  * 8 + l], w7  = qp[(size_t)s7  * 8 + l];
            unsigned w8  = qp[(size_t)s8  * 8 + l], w9  = qp[(size_t)s9  * 8 + l];
            unsigned w10 = qp[(size_t)s10 * 8 + l], w11 = qp[(size_t)s11 * 8 + l];
            unsigned w12 = qp[(size_t)s12 * 8 + l], w13 = qp[(size_t)s13 * 8 + l];
            unsigned w14 = qp[(size_t)s14 * 8 + l], w15 = qp[(size_t)s15 * 8 + l];
            float2 a = make_float2(0.f, 0.f);
            accu(a, w16);
            accu(a, w0);  accu(a, w1);  accu(a, w2);  accu(a, w3);
            accu(a, w4);  accu(a, w5);  accu(a, w6);  accu(a, w7);
            accu(a, w8);  accu(a, w9);  accu(a, w10); accu(a, w11);
            accu(a, w12); accu(a, w13); accu(a, w14); accu(a, w15);
            if (big) {
                unsigned u0  = qp[(size_t)t0  * 8 + l], u1  = qp[(size_t)t1  * 8 + l];
                unsigned u2  = qp[(size_t)t2  * 8 + l], u3  = qp[(size_t)t3  * 8 + l];
                unsigned u4  = qp[(size_t)t4  * 8 + l], u5  = qp[(size_t)t5  * 8 + l];
                unsigned u6  = qp[(size_t)t6  * 8 + l], u7  = qp[(size_t)t7  * 8 + l];
                unsigned u8  = qp[(size_t)t8  * 8 + l], u9  = qp[(size_t)t9  * 8 + l];
                unsigned u10 = qp[(size_t)t10 * 8 + l], u11 = qp[(size_t)t11 * 8 + l];
                unsigned u12 = qp[(size_t)t12 * 8 + l], u13 = qp[(size_t)t13 * 8 + l];
                unsigned u14 = qp[(size_t)t14 * 8 + l], u15 = qp[(size_t)t15 * 8 + l];
                accu(a, u0);  accu(a, u1);  accu(a, u2);  accu(a, u3);
                accu(a, u4);  accu(a, u5);  accu(a, u6);  accu(a, u7);
                accu(a, u8);  accu(a, u9);  accu(a, u10); accu(a, u11);
                accu(a, u12); accu(a, u13); accu(a, u14); accu(a, u15);
            }
            for (int i = 0; i < c; ++i) {
                if (ovf[2 * i + 1] == n) accu(a, qp[(size_t)ovf[2 * i] * 8 + l]);
            }
            sAgg[o][ph * 16 + 2 * l]     = a.x;
            sAgg[o][ph * 16 + 2 * l + 1] = a.y;
        }
    }
    __syncthreads();
    int ln = tid >> 6, j = tid & 63;   // 4 waves x 64 feats
#pragma unroll
    for (int nn = 0; nn < 8; ++nn) {
        int ol = nn * 4 + ln;
        int node = nb + ol;
        if (node < N) {
            float s = 0.f;
#pragma unroll
            for (int k = 0; k < 32; ++k) s += sAgg[ol][k] * Ws[k * 64 + j];
            __builtin_nontemporal_store(dinv[node] * s + b2[j], &out[(size_t)node * 64 + j]);
        }
    }
}

extern "C" void kernel_launch(void* const* d_in, const int* in_sizes, int n_in,
                              void* d_out, int out_size, void* d_ws, size_t ws_size,
                              hipStream_t stream) {
    const float* x  = (const float*)d_in[0];
    const int*   ei = (const int*)d_in[1];   // int32, shape (2,E) flat
    const float* W1 = (const float*)d_in[2];
    const float* b1 = (const float*)d_in[3];
    const float* W2 = (const float*)d_in[4];
    const float* b2 = (const float*)d_in[5];
    float* out = (float*)d_out;

    int N = in_sizes[0] / 64;        // 100000
    int E = in_sizes[1] / 2;         // 1200000
    const int* src = ei;
    const int* dst = ei + (size_t)E;
    int B = (N + SH - 1) >> SH_BITS; // 391 buckets

    // ws (NO aliasing): dinv[N] f | ga[8(N+1)] | gb[8(N+1)] | qa[8(N+1)] |
    // qb[8(N+1)] u32 | ebuf[B*BCAP] u32 | adj[32N] i | bcur[512] | ovfcnt[4] |
    // ovf[2*OVF_MAX]   (~33 MB)
    size_t NP = (size_t)N + 1;
    float* dinv = (float*)d_ws;
    unsigned* ga = (unsigned*)(dinv + N);
    unsigned* gb = ga + 8 * NP;
    unsigned* qa = gb + 8 * NP;
    unsigned* qb = qa + 8 * NP;
    unsigned* ebuf = qb + 8 * NP;                 // dedicated region
    int* adj    = (int*)(ebuf + (size_t)B * BCAP);
    int* bcur   = adj + (size_t)CAP * N;
    int* ovfcnt = bcur + 512;
    int* ovf    = ovfcnt + 4;

    init_kernel<<<(B + 255) / 256, 256, 0, stream>>>(
        bcur, ovfcnt, ga + 8 * (size_t)N, gb + 8 * (size_t)N,
        qa + 8 * (size_t)N, qb + 8 * (size_t)N, B);
    bin_kernel<<<(E + EPB - 1) / EPB, 256, 0, stream>>>(src, dst, bcur, ebuf, ovfcnt, ovf, E, B);
    fillb_kernel<<<B, 256, 0, stream>>>(ebuf, bcur, adj, dinv, ovfcnt, ovf, N);

    gemm1_kernel<<<(N + 15) / 16, 256, 0, stream>>>(x, W1, dinv, ga, gb, N);

    int nbHalf = (N + 31) / 32;      // 3125 blocks per plane
    gather_q_kernel<<<2 * nbHalf, 256, 0, stream>>>(
        (const int2*)adj, ovfcnt, ovf, ga, gb, dinv, b1, qa, qb, N, nbHalf);
    gather_out_kernel<<<(N + 31) / 32, 256, 0, stream>>>(
        (const int2*)adj, ovfcnt, ovf, qa, qb, dinv, W2, b2, out, N);
}

// Round 14
// 179.859 us; speedup vs baseline: 1.0680x; 1.0680x over previous
//
#include <hip/hip_runtime.h>

// GCN 2-layer forward. Fixed-stride bucketed padded-CSR build (bin/fillb),
// gather-only aggregation with BF16 message rows (64B/row): 8 lanes per node,
// lane l holds features 4l..4l+3 as two bf16x2; accumulation in fp32.
// mid fused into gather-1, gemm2 fused into gather-2. Weights/outputs fp32.
//
// FINAL STRUCTURE (= R10, best measured 178.2us). R13's planar split
// regressed (192us: 2x adj reads + 2x dispatch overhead > L2 hit gain);
// R11's gating/NT micro-opts were neutral; R9's issue-width change neutral.
// The gathers sit at the L2/LLC random-access service floor for a 6.4MB
// bf16 footprint; fp8 would break the absmax threshold.

#define CAP 32
#define OVF_MAX 65536
#define SH_BITS 8
#define SH 256          // nodes per bucket
#define BCAP 3584       // edge capacity per bucket (E/B ~ 3070, sigma ~ 55)
#define EPB 4096        // edges per bin block
#define EPT 16          // edges per thread in bin

__device__ __forceinline__ unsigned bf16rn(float f) {
    unsigned u = __float_as_uint(f);
    return (u + 0x7fffu + ((u >> 16) & 1u)) >> 16;   // round-to-nearest-even
}
__device__ __forceinline__ unsigned pack2(float f0, float f1) {
    return (bf16rn(f1) << 16) | bf16rn(f0);
}
__device__ __forceinline__ void acc2(float4& a, uint2 v) {
    a.x += __uint_as_float(v.x << 16);
    a.y += __uint_as_float(v.x & 0xffff0000u);
    a.z += __uint_as_float(v.y << 16);
    a.w += __uint_as_float(v.y & 0xffff0000u);
}

__global__ void init_kernel(int* __restrict__ bcur, int* __restrict__ ovfcnt,
                            unsigned int* __restrict__ g1rowN,
                            unsigned int* __restrict__ q1rowN, int B) {
    int i = blockIdx.x * blockDim.x + threadIdx.x;
    if (i < B) bcur[i] = i * BCAP;
    if (i == 0) *ovfcnt = 0;
    if (i < 16) { g1rowN[i] = 0u; q1rowN[i] = 0u; }   // sentinel zero-rows (bf16 0 == 0u)
}

// Bin edges into fixed-stride bucket runs, payload packed to 4B:
// (dst&255)<<24 | src. The histogram atomicAdd's return value is kept as the
// block-local rank (no second rank-atomic pass). One cursor atomic per touched
// bucket. Bucket-cap spill -> exact global overflow list (P ~ 1e-19).
__global__ __launch_bounds__(256) void bin_kernel(const int* __restrict__ src,
                                                  const int* __restrict__ dst,
                                                  int* __restrict__ bcur,
                                                  unsigned int* __restrict__ ebuf,
                                                  int* __restrict__ ovfcnt,
                                                  int* __restrict__ ovf, int E, int B) {
    __shared__ int h[512];
    __shared__ int gp[512];
    for (int b = threadIdx.x; b < B; b += 256) h[b] = 0;
    __syncthreads();
    int base = blockIdx.x * EPB;
    int s[EPT], d[EPT], r[EPT];
#pragma unroll
    for (int k = 0; k < EPT; ++k) {
        int e = base + k * 256 + threadIdx.x;
        bool ok = e < E;
        s[k] = ok ? src[e] : 0;
        d[k] = ok ? dst[e] : 0;
        r[k] = ok ? atomicAdd(&h[d[k] >> SH_BITS], 1) : 0;   // rank = pre-count
    }
    __syncthreads();
    for (int b = threadIdx.x; b < B; b += 256)
        if (h[b]) gp[b] = atomicAdd(&bcur[b], h[b]);
    __syncthreads();
#pragma unroll
    for (int k = 0; k < EPT; ++k) {
        int e = base + k * 256 + threadIdx.x;
        if (e < E) {
            int bk = d[k] >> SH_BITS;
            int pos = gp[bk] + r[k];
            if (pos < (bk + 1) * BCAP)
                ebuf[pos] = ((unsigned)(d[k] & (SH - 1)) << 24) | (unsigned)s[k];
            else { int o = atomicAdd(ovfcnt, 1); if (o < OVF_MAX) { ovf[2 * o] = s[k]; ovf[2 * o + 1] = d[k]; } }
        }
    }
}

// One block per bucket: build the 256-node padded-CSR window in LDS, pad
// unused slots with sentinel N (-> zeroed g row), stream out dense. Rows with
// deg<16 skip their all-sentinel second half (never read: gather gates on
// slot15 != N <=> deg >= 16).
__global__ __launch_bounds__(256) void fillb_kernel(const unsigned int* __restrict__ ebuf,
                                                    const int* __restrict__ bcur,
                                                    int* __restrict__ adj,
                                                    float* __restrict__ dinv,
                                                    int* __restrict__ ovfcnt,
                                                    int* __restrict__ ovf, int N) {
    __shared__ int lcnt[SH];
    __shared__ int ladj[SH * CAP];     // 32 KB
    int b = blockIdx.x;
    for (int i = threadIdx.x; i < SH; i += 256) lcnt[i] = 0;
    for (int i = threadIdx.x; i < SH * CAP; i += 256) ladj[i] = N;   // sentinel pad
    __syncthreads();
    int beg = b * BCAP;
    int tot = bcur[b] - beg;
    int m = tot < BCAP ? tot : BCAP;
    for (int i = threadIdx.x; i < m; i += 256) {
        unsigned p = ebuf[beg + i];
        int ld = (int)(p >> 24), sidx = (int)(p & 0xFFFFFF);
        int q = atomicAdd(&lcnt[ld], 1);
        if (q < CAP) ladj[ld * CAP + q] = sidx;
        else { int o = atomicAdd(ovfcnt, 1); if (o < OVF_MAX) { ovf[2 * o] = sidx; ovf[2 * o + 1] = (b << SH_BITS) + ld; } }
    }
    __syncthreads();
    int nb0 = b << SH_BITS;
    const int4* l4 = (const int4*)ladj;
    int4* a4 = (int4*)(adj + (size_t)nb0 * CAP);
    for (int i = threadIdx.x; i < SH * CAP / 4; i += 256) {
        int row = i >> 3;                  // 8 int4 per 32-slot row
        int nd = nb0 + row;
        bool second = (i & 4) != 0;        // int4s 4..7 = slots 16..31
        if (nd < N && (!second || lcnt[row] >= 16)) a4[i] = l4[i];
    }
    for (int i = threadIdx.x; i < SH; i += 256) {
        int nd = nb0 + i;
        if (nd < N) dinv[nd] = rsqrtf((float)lcnt[i] + 1.0f);   // +1 = self-loop
    }
}

// g1 = bf16( dinv * (x @ W1) ). Block = 16 nodes x 16 lanes; each lane computes
// feature pair (2j, 2j+1) and writes one packed uint. Row = 16 uints = 64B.
__global__ __launch_bounds__(256) void gemm1_kernel(const float* __restrict__ x,
                                                    const float* __restrict__ W1,
                                                    const float* __restrict__ dinv,
                                                    unsigned int* __restrict__ g1, int N) {
    __shared__ float Ws[64 * 32];
    __shared__ float xs[16][64];
    int tid = threadIdx.x;
    const float4* W4 = (const float4*)W1;
    float4* Ws4 = (float4*)Ws;
    for (int i = tid; i < 512; i += 256) Ws4[i] = W4[i];
    int nb = blockIdx.x * 16;
    {
        int ln = tid >> 4, k4 = (tid & 15) * 4;
        int n = nb + ln;
        float4 v = make_float4(0.f, 0.f, 0.f, 0.f);
        if (n < N) v = *(const float4*)(x + (size_t)n * 64 + k4);
        *(float4*)(&xs[ln][k4]) = v;
    }
    __syncthreads();
    int ln = tid >> 4, j = tid & 15;
    int n = nb + ln;
    if (n < N) {
        float s0 = 0.f, s1 = 0.f;
#pragma unroll
        for (int k = 0; k < 64; ++k) {
            float xv = xs[ln][k];
            s0 += xv * Ws[k * 32 + 2 * j];
            s1 += xv * Ws[k * 32 + 2 * j + 1];
        }
        float dv = dinv[n];
        g1[(size_t)n * 16 + j] = pack2(dv * s0, dv * s1);
    }
}

// 8 lanes per node: lane l holds features 4l..4l+3 (uint2 of bf16x2) and
// neighbor slots {2l,2l+1} per 64B adj half (int2). Half 2 (slots 16..31) is
// loaded + gathered only when slot 15 != N (deg >= 16, ~10% of nodes).
__device__ __forceinline__ float4 gather_row4(const int2* __restrict__ adj2,
                                              const int* __restrict__ ovfcnt,
                                              const int* __restrict__ ovf,
                                              const uint2* __restrict__ g2,
                                              int n, int l, int N) {
    int2 h1 = adj2[(size_t)n * 16 + l];    // slots 2l, 2l+1
    float4 a = make_float4(0.f, 0.f, 0.f, 0.f);
    uint2 self = g2[(size_t)n * 8 + l];
    int s15;
    {
        int s0  = __shfl(h1.x, 0, 8), s1  = __shfl(h1.y, 0, 8);
        int s2  = __shfl(h1.x, 1, 8), s3  = __shfl(h1.y, 1, 8);
        int s4  = __shfl(h1.x, 2, 8), s5  = __shfl(h1.y, 2, 8);
        int s6  = __shfl(h1.x, 3, 8), s7  = __shfl(h1.y, 3, 8);
        int s8  = __shfl(h1.x, 4, 8), s9  = __shfl(h1.y, 4, 8);
        int s10 = __shfl(h1.x, 5, 8), s11 = __shfl(h1.y, 5, 8);
        int s12 = __shfl(h1.x, 6, 8), s13 = __shfl(h1.y, 6, 8);
        int s14 = __shfl(h1.x, 7, 8); s15 = __shfl(h1.y, 7, 8);
        uint2 v0  = g2[(size_t)s0  * 8 + l], v1  = g2[(size_t)s1  * 8 + l];
        uint2 v2  = g2[(size_t)s2  * 8 + l], v3  = g2[(size_t)s3  * 8 + l];
        uint2 v4  = g2[(size_t)s4  * 8 + l], v5  = g2[(size_t)s5  * 8 + l];
        uint2 v6  = g2[(size_t)s6  * 8 + l], v7  = g2[(size_t)s7  * 8 + l];
        uint2 v8  = g2[(size_t)s8  * 8 + l], v9  = g2[(size_t)s9  * 8 + l];
        uint2 v10 = g2[(size_t)s10 * 8 + l], v11 = g2[(size_t)s11 * 8 + l];
        uint2 v12 = g2[(size_t)s12 * 8 + l], v13 = g2[(size_t)s13 * 8 + l];
        uint2 v14 = g2[(size_t)s14 * 8 + l], v15 = g2[(size_t)s15 * 8 + l];
        acc2(a, self);
        acc2(a, v0);  acc2(a, v1);  acc2(a, v2);  acc2(a, v3);
        acc2(a, v4);  acc2(a, v5);  acc2(a, v6);  acc2(a, v7);
        acc2(a, v8);  acc2(a, v9);  acc2(a, v10); acc2(a, v11);
        acc2(a, v12); acc2(a, v13); acc2(a, v14); acc2(a, v15);
    }
    if (s15 != N) {                        // deg >= 16: second half exists
        int2 h2 = adj2[(size_t)n * 16 + 8 + l];   // slots 16+2l, 17+2l
        int s0  = __shfl(h2.x, 0, 8), s1  = __shfl(h2.y, 0, 8);
        int s2  = __shfl(h2.x, 1, 8), s3  = __shfl(h2.y, 1, 8);
        int s4  = __shfl(h2.x, 2, 8), s5  = __shfl(h2.y, 2, 8);
        int s6  = __shfl(h2.x, 3, 8), s7  = __shfl(h2.y, 3, 8);
        int s8  = __shfl(h2.x, 4, 8), s9  = __shfl(h2.y, 4, 8);
        int s10 = __shfl(h2.x, 5, 8), s11 = __shfl(h2.y, 5, 8);
        int s12 = __shfl(h2.x, 6, 8), s13 = __shfl(h2.y, 6, 8);
        int s14 = __shfl(h2.x, 7, 8), sl15 = __shfl(h2.y, 7, 8);
        uint2 v0  = g2[(size_t)s0  * 8 + l], v1  = g2[(size_t)s1  * 8 + l];
        uint2 v2  = g2[(size_t)s2  * 8 + l], v3  = g2[(size_t)s3  * 8 + l];
        uint2 v4  = g2[(size_t)s4  * 8 + l], v5  = g2[(size_t)s5  * 8 + l];
        uint2 v6  = g2[(size_t)s6  * 8 + l], v7  = g2[(size_t)s7  * 8 + l];
        uint2 v8  = g2[(size_t)s8  * 8 + l], v9  = g2[(size_t)s9  * 8 + l];
        uint2 v10 = g2[(size_t)s10 * 8 + l], v11 = g2[(size_t)s11 * 8 + l];
        uint2 v12 = g2[(size_t)s12 * 8 + l], v13 = g2[(size_t)s13 * 8 + l];
        uint2 v14 = g2[(size_t)s14 * 8 + l], v15 = g2[(size_t)sl15 * 8 + l];
        acc2(a, v0);  acc2(a, v1);  acc2(a, v2);  acc2(a, v3);
        acc2(a, v4);  acc2(a, v5);  acc2(a, v6);  acc2(a, v7);
        acc2(a, v8);  acc2(a, v9);  acc2(a, v10); acc2(a, v11);
        acc2(a, v12); acc2(a, v13); acc2(a, v14); acc2(a, v15);
    }
    int c = *ovfcnt; if (c > OVF_MAX) c = OVF_MAX;   // ~always 0
    for (int i = 0; i < c; ++i) {
        if (ovf[2 * i + 1] == n) acc2(a, g2[(size_t)ovf[2 * i] * 8 + l]);
    }
    return a;
}

// Layer-1 aggregate + fused mid: q = bf16( dinv * relu(dinv*agg + b1) ).
__global__ void gather_q_kernel(const int2* __restrict__ adj2,
                                const int* __restrict__ ovfcnt, const int* __restrict__ ovf,
                                const uint2* __restrict__ g2, const float* __restrict__ dinv,
                                const float* __restrict__ b1, uint2* __restrict__ q2, int N) {
    int tid = blockIdx.x * blockDim.x + threadIdx.x;
    int n = tid >> 3, l = tid & 7;
    if (n < N) {
        float4 a = gather_row4(adj2, ovfcnt, ovf, g2, n, l, N);
        float dv = dinv[n];
        float4 bb = ((const float4*)b1)[l];
        float vx = dv * a.x + bb.x, vy = dv * a.y + bb.y;
        float vz = dv * a.z + bb.z, vw = dv * a.w + bb.w;
        vx = vx > 0.f ? vx : 0.f; vy = vy > 0.f ? vy : 0.f;
        vz = vz > 0.f ? vz : 0.f; vw = vw > 0.f ? vw : 0.f;
        q2[(size_t)n * 8 + l] = make_uint2(pack2(dv * vx, dv * vy), pack2(dv * vz, dv * vw));
    }
}

// Layer-2 aggregate + fused gemm2: out[n,:] = dinv[n]*(agg2[n,:] @ W2) + b2.
// Block = 256 thr = 32 nodes (8 lanes each); agg staged in LDS (fp32).
// out stores are nontemporal (never re-read) to keep q rows L2-resident.
__global__ __launch_bounds__(256) void gather_out_kernel(
        const int2* __restrict__ adj2,
        const int* __restrict__ ovfcnt, const int* __restrict__ ovf,
        const uint2* __restrict__ q2, const float* __restrict__ dinv,
        const float* __restrict__ W2, const float* __restrict__ b2,
        float* __restrict__ out, int N) {
    __shared__ float Ws[32 * 64];
    __shared__ float sAgg[32][36];     // stride 36: float4-aligned, conflict-free
    int tid = threadIdx.x;
    const float4* W4 = (const float4*)W2;
    float4* Ws4 = (float4*)Ws;
    for (int i = tid; i < 512; i += 256) Ws4[i] = W4[i];
    int nb = blockIdx.x * 32;
    int o = tid >> 3, l = tid & 7;
    int n = nb + o;
    if (n < N) *(float4*)(&sAgg[o][l * 4]) = gather_row4(adj2, ovfcnt, ovf, q2, n, l, N);
    __syncthreads();
    int ln = tid >> 6, j = tid & 63;   // 4 waves x 64 feats
#pragma unroll
    for (int nn = 0; nn < 8; ++nn) {
        int ol = nn * 4 + ln;
        int node = nb + ol;
        if (node < N) {
            float s = 0.f;
#pragma unroll
            for (int k = 0; k < 32; ++k) s += sAgg[ol][k] * Ws[k * 64 + j];
            __builtin_nontemporal_store(dinv[node] * s + b2[j], &out[(size_t)node * 64 + j]);
        }
    }
}

extern "C" void kernel_launch(void* const* d_in, const int* in_sizes, int n_in,
                              void* d_out, int out_size, void* d_ws, size_t ws_size,
                              hipStream_t stream) {
    const float* x  = (const float*)d_in[0];
    const int*   ei = (const int*)d_in[1];   // int32, shape (2,E) flat
    const float* W1 = (const float*)d_in[2];
    const float* b1 = (const float*)d_in[3];
    const float* W2 = (const float*)d_in[4];
    const float* b2 = (const float*)d_in[5];
    float* out = (float*)d_out;

    int N = in_sizes[0] / 64;        // 100000
    int E = in_sizes[1] / 2;         // 1200000
    const int* src = ei;
    const int* dst = ei + (size_t)E;
    int B = (N + SH - 1) >> SH_BITS; // 391 buckets

    // ws: dinv[N] f | g1[16(N+1)] u32 (bf16 rows) | q1[16(N+1)] u32 (aliases
    // ebuf[B*BCAP]=5.6MB < q1 6.4MB; q1's sentinel row at offset 16N = 1.6M
    // uints sits BEYOND ebuf's 1.4M extent — safe; ebuf dead before gather_q
    // writes q1) | adj[32N] i | bcur[512] i | ovfcnt[4] i | ovf[2*OVF_MAX] i
    size_t NP = (size_t)N + 1;
    float* dinv   = (float*)d_ws;
    unsigned int* g1 = (unsigned int*)(dinv + N);
    unsigned int* q1 = g1 + 16 * NP;
    unsigned int* ebuf = q1;
    int*   adj    = (int*)(q1 + 16 * NP);
    int*   bcur   = adj + (size_t)CAP * N;
    int*   ovfcnt = bcur + 512;
    int*   ovf    = ovfcnt + 4;

    init_kernel<<<(B + 255) / 256, 256, 0, stream>>>(bcur, ovfcnt,
                                                     g1 + 16 * (size_t)N, q1 + 16 * (size_t)N, B);
    bin_kernel<<<(E + EPB - 1) / EPB, 256, 0, stream>>>(src, dst, bcur, ebuf, ovfcnt, ovf, E, B);
    fillb_kernel<<<B, 256, 0, stream>>>(ebuf, bcur, adj, dinv, ovfcnt, ovf, N);

    gemm1_kernel<<<(N + 15) / 16, 256, 0, stream>>>(x, W1, dinv, g1, N);

    long long tq = (long long)N * 8;
    gather_q_kernel<<<(int)((tq + 255) / 256), 256, 0, stream>>>(
        (const int2*)adj, ovfcnt, ovf, (const uint2*)g1, dinv, b1, (uint2*)q1, N);
    gather_out_kernel<<<(N + 31) / 32, 256, 0, stream>>>(
        (const int2*)adj, ovfcnt, ovf, (const uint2*)q1, dinv, W2, b2, out, N);
}